// Round 11
// baseline (684.908 us; speedup 1.0000x reference)
//
#include <hip/hip_runtime.h>
#include <hip/hip_cooperative_groups.h>
#include <math.h>

#define H 768
#define S 256
#define NB 4      // batch
#define TOPK 4
#define L 4
#define NH 6      // biaffine h-split chunks (128 h each) -> 1536 units = 2/block
#define GRID 768  // persistent grid: 3 blocks/CU (LDS 51.2 KB caps at 3)

// 2/ln2: tanh(x) = 1 - 2/(2^(C*x)+1)
#define CSCALE 2.8853900817779268f

typedef __bf16 bf16x8 __attribute__((ext_vector_type(8)));
typedef __bf16 bf16x4 __attribute__((ext_vector_type(4)));
typedef float floatx4 __attribute__((ext_vector_type(4)));

__device__ __forceinline__ float exp2_native(float x) {
#if __has_builtin(__builtin_amdgcn_exp2f)
  return __builtin_amdgcn_exp2f(x);
#else
  float r; asm("v_exp_f32 %0, %1" : "=v"(r) : "v"(x)); return r;
#endif
}
__device__ __forceinline__ float rcp_native(float x) {
#if __has_builtin(__builtin_amdgcn_rcpf)
  return __builtin_amdgcn_rcpf(x);
#else
  float r; asm("v_rcp_f32 %0, %1" : "=v"(r) : "v"(x)); return r;
#endif
}
__device__ __forceinline__ float fast_tanh(float x) {
  float cx = fminf(15.f, fmaxf(-15.f, x));
  float e = __expf(cx + cx);
  return __fdividef(e - 1.f, e + 1.f);
}

struct Params {
  const float *pooled, *Wa_w, *Ua_w, *dense_w, *Wa_b, *Ua_b, *dense_b, *va, *fc_w, *fc_b;
  float *hij, *partials, *logits, *out_type;
  __bf16 *Wh, *Wl, *Drow, *dpb, *hpb, *Ah, *Al;
};

// LDS union across phases (max = GEMM's 51,200 B)
union Smem {
  struct { __bf16 Ahs[2][32][40], Als[2][32][40], Bhs[2][128][40], Bls[2][128][40]; } g;
  struct { float his[2][16][34], hjs[2][16][34], vas2[128], svas; } b;
};

// ---------------------------------------------------------------------------
// Phase 0: fp32 -> bf16 conversions (one-shot; rounding identical to r6-r10).
__device__ __forceinline__ void cvt_phase(const Params& P, int gid, int gstride) {
  const int NA4 = (NB * S * H) / 4;       // 196608
  const int NW4 = (2 * H * H) / 4;        // 294912
  const int NWa4 = (H * H) / 4;           // 147456
  const int ND4 = (H * 2 * H) / 4;        // 294912
  for (int i = gid; i < NA4 + NW4 + ND4; i += gstride) {
    if (i >= NA4 + NW4) {  // dense_w -> Drow (hi only), dep/head split rows
      int w = i - NA4 - NW4;
      int o = w / 384;
      int k = (w - o * 384) * 4;
      float4 v = ((const float4*)P.dense_w)[w];
      union { __bf16 h[4]; ushort4 u; } tmp;
      tmp.h[0] = (__bf16)v.x; tmp.h[1] = (__bf16)v.y;
      tmp.h[2] = (__bf16)v.z; tmp.h[3] = (__bf16)v.w;
      int row = (k < H) ? o : (H + o);
      int col = (k < H) ? k : (k - H);
      *(ushort4*)(P.Drow + (size_t)row * H + col) = tmp.u;
      continue;
    }
    float4 v;
    __bf16 *hi, *lo;
    if (i < NA4) {
      v = ((const float4*)P.pooled)[i];
      hi = P.Ah + (size_t)i * 4; lo = P.Al + (size_t)i * 4;
    } else {
      int w = i - NA4;
      v = (w < NWa4) ? ((const float4*)P.Wa_w)[w] : ((const float4*)P.Ua_w)[w - NWa4];
      hi = P.Wh + (size_t)w * 4; lo = P.Wl + (size_t)w * 4;
    }
    union { __bf16 h[4]; ushort4 u; } a, b;
    float f[4] = {v.x, v.y, v.z, v.w};
#pragma unroll
    for (int k = 0; k < 4; ++k) {
      __bf16 h = (__bf16)f[k];
      a.h[k] = h;
      b.h[k] = (__bf16)(f[k] - (float)h);
    }
    *(ushort4*)hi = a.u;
    *(ushort4*)lo = b.u;
  }
}

// ---------------------------------------------------------------------------
// Phase 1: one GEMM tile (r10 mega body): C = pooled(1024x768) @ B^T.
// B rows 0..1535 = concat(Wa,Ua) hi/lo (3-term -> hij, CSCALE); 1536..2303 =
// dense dep (+dense_b -> dpb); 2304..3071 = head (-> hpb).
__device__ __forceinline__ void mega_phase(const Params& P, Smem& smu, int bid, int t) {
  auto& sm = smu.g;
  const int m0 = (bid & 31) * 32;
  const int g = bid >> 5;                          // 0..23
  const int ng = (g & 1) ? (12 + (g >> 1)) : (g >> 1);
  const int n0 = ng * 128;
  const bool isproj = (ng < 12);
  const int arow = t >> 3;
  const int ka = (t & 7) * 4;
  const __bf16* Arh = P.Ah + (size_t)(m0 + arow) * H;
  const __bf16* Arl = P.Al + (size_t)(m0 + arow) * H;
  const int brow = t >> 1;
  const int kb = (t & 1) * 16;
  const int ncol = n0 + brow;
  const __bf16* Brh = isproj ? (P.Wh + (size_t)ncol * H)
                             : (P.Drow + (size_t)(ncol - 2 * H) * H);
  const __bf16* Brl = P.Wl + (size_t)(isproj ? ncol : brow) * H;  // unused if !isproj
  const int lane = t & 63;
  const int wave = t >> 6;
  const int wn = wave * 32;
  const int fm = lane & 15;
  const int quad = lane >> 4;
  floatx4 acc[2][2] = {};

  ushort4 a_h = *(const ushort4*)&Arh[ka];
  ushort4 a_l = *(const ushort4*)&Arl[ka];
  bf16x8 b_h0 = *(const bf16x8*)&Brh[kb];
  bf16x8 b_h1 = *(const bf16x8*)&Brh[kb + 8];
  bf16x8 b_l0 = {}, b_l1 = {};
  if (isproj) {
    b_l0 = *(const bf16x8*)&Brl[kb];
    b_l1 = *(const bf16x8*)&Brl[kb + 8];
  }

  for (int kc = 0; kc < H; kc += 32) {
    const int bfx = (kc >> 5) & 1;
    *(ushort4*)&sm.Ahs[bfx][arow][ka] = a_h;
    *(ushort4*)&sm.Als[bfx][arow][ka] = a_l;
    *(bf16x8*)&sm.Bhs[bfx][brow][kb] = b_h0;
    *(bf16x8*)&sm.Bhs[bfx][brow][kb + 8] = b_h1;
    if (isproj) {
      *(bf16x8*)&sm.Bls[bfx][brow][kb] = b_l0;
      *(bf16x8*)&sm.Bls[bfx][brow][kb + 8] = b_l1;
    }
    __syncthreads();
    if (kc + 32 < H) {
      a_h = *(const ushort4*)&Arh[kc + 32 + ka];
      a_l = *(const ushort4*)&Arl[kc + 32 + ka];
      b_h0 = *(const bf16x8*)&Brh[kc + 32 + kb];
      b_h1 = *(const bf16x8*)&Brh[kc + 32 + kb + 8];
      if (isproj) {
        b_l0 = *(const bf16x8*)&Brl[kc + 32 + kb];
        b_l1 = *(const bf16x8*)&Brl[kc + 32 + kb + 8];
      }
    }
    bf16x8 afh[2], bfh[2];
#pragma unroll
    for (int i = 0; i < 2; ++i) {
      afh[i] = *(const bf16x8*)&sm.Ahs[bfx][i * 16 + fm][quad * 8];
      bfh[i] = *(const bf16x8*)&sm.Bhs[bfx][wn + i * 16 + fm][quad * 8];
    }
    if (isproj) {
      bf16x8 afl[2], bfl[2];
#pragma unroll
      for (int i = 0; i < 2; ++i) {
        afl[i] = *(const bf16x8*)&sm.Als[bfx][i * 16 + fm][quad * 8];
        bfl[i] = *(const bf16x8*)&sm.Bls[bfx][wn + i * 16 + fm][quad * 8];
      }
#pragma unroll
      for (int i = 0; i < 2; ++i)
#pragma unroll
        for (int j = 0; j < 2; ++j) {  // per-acc order hh,hl,lh == r7-r10
          acc[i][j] = __builtin_amdgcn_mfma_f32_16x16x32_bf16(afh[i], bfh[j], acc[i][j], 0, 0, 0);
          acc[i][j] = __builtin_amdgcn_mfma_f32_16x16x32_bf16(afh[i], bfl[j], acc[i][j], 0, 0, 0);
          acc[i][j] = __builtin_amdgcn_mfma_f32_16x16x32_bf16(afl[i], bfh[j], acc[i][j], 0, 0, 0);
        }
    } else {
#pragma unroll
      for (int i = 0; i < 2; ++i)
#pragma unroll
        for (int j = 0; j < 2; ++j)
          acc[i][j] = __builtin_amdgcn_mfma_f32_16x16x32_bf16(afh[i], bfh[j], acc[i][j], 0, 0, 0);
    }
  }
#pragma unroll
  for (int j = 0; j < 2; ++j) {
    const int col = n0 + wn + j * 16 + fm;
    if (col < 2 * H) {
      const float bias = (col < H) ? P.Wa_b[col] : P.Ua_b[col - H];
#pragma unroll
      for (int i = 0; i < 2; ++i)
#pragma unroll
        for (int rg = 0; rg < 4; ++rg) {
          const int row = m0 + i * 16 + quad * 4 + rg;
          P.hij[(size_t)row * 1536 + col] = CSCALE * (acc[i][j][rg] + bias);
        }
    } else if (col < 3 * H) {
      const int o = col - 2 * H;
      const float bias = P.dense_b[o];
#pragma unroll
      for (int i = 0; i < 2; ++i)
#pragma unroll
        for (int rg = 0; rg < 4; ++rg) {
          const int row = m0 + i * 16 + quad * 4 + rg;
          P.dpb[(size_t)row * H + o] = (__bf16)(acc[i][j][rg] + bias);
        }
    } else {
      const int o = col - 3 * H;
#pragma unroll
      for (int i = 0; i < 2; ++i)
#pragma unroll
        for (int rg = 0; rg < 4; ++rg) {
          const int row = m0 + i * 16 + quad * 4 + rg;
          P.hpb[(size_t)row * H + o] = (__bf16)acc[i][j][rg];
        }
    }
  }
}

// ---------------------------------------------------------------------------
// Phase 2 (one unit): partial[ch][b,a,c] = Sva_ch + sum_{128h} (-2 va)*rcp(2^(xi+xj)+1)
// (r5-r10 validated pipeline; at the transcendental-pipe roofline)
__device__ __forceinline__ void biaffine_unit(const Params& P, Smem& smu, int u, int t) {
  auto& sm = smu.b;
  const int cx = u & 7, ay = (u >> 3) & 7, z = u >> 6;  // z 0..23
  const int b = z / NH, ch = z - b * NH;
  const int hc0 = ch * 128;
  const int a0 = ay * 32, c0 = cx * 32;
  __syncthreads();  // protect LDS reuse across units / phases
  if (t < 128) sm.vas2[t] = -2.f * P.va[hc0 + t];
  __syncthreads();
  if (t < 64) {
    float s = sm.vas2[t] + sm.vas2[t + 64];
#pragma unroll
    for (int off = 32; off > 0; off >>= 1) s += __shfl_xor(s, off);
    if (t == 0) sm.svas = -0.5f * s;
  }
  const int lh = t & 15;
  const int lr = t >> 4;
  const int ca = (t & 15) * 2;
  const int aa = (t >> 4) * 2;
  const float* pi0b = P.hij + (size_t)(b * S + c0 + lr) * 1536 + hc0 + lh;
  const float* pi1b = P.hij + (size_t)(b * S + c0 + lr + 16) * 1536 + hc0 + lh;
  const float* pj0b = P.hij + (size_t)(b * S + a0 + lr) * 1536 + 768 + hc0 + lh;
  const float* pj1b = P.hij + (size_t)(b * S + a0 + lr + 16) * 1536 + 768 + hc0 + lh;
  float acc00 = 0.f, acc01 = 0.f, acc10 = 0.f, acc11 = 0.f;

  float pi0 = pi0b[0], pi1 = pi1b[0], pj0 = pj0b[0], pj1 = pj1b[0];
  for (int hr = 0; hr < 128; hr += 16) {
    const int bf = (hr >> 4) & 1;
    sm.his[bf][lh][lr]      = pi0;
    sm.his[bf][lh][lr + 16] = pi1;
    sm.hjs[bf][lh][lr]      = pj0;
    sm.hjs[bf][lh][lr + 16] = pj1;
    __syncthreads();
    if (hr + 16 < 128) {
      pi0 = pi0b[hr + 16]; pi1 = pi1b[hr + 16];
      pj0 = pj0b[hr + 16]; pj1 = pj1b[hr + 16];
    }
    float vreg[16];
    *(float4*)&vreg[0]  = *(const float4*)&sm.vas2[hr + 0];
    *(float4*)&vreg[4]  = *(const float4*)&sm.vas2[hr + 4];
    *(float4*)&vreg[8]  = *(const float4*)&sm.vas2[hr + 8];
    *(float4*)&vreg[12] = *(const float4*)&sm.vas2[hr + 12];
#pragma unroll
    for (int h = 0; h < 16; ++h) {
      float v = vreg[h];
      float2 xi = *(const float2*)&sm.his[bf][h][ca];
      float2 xj = *(const float2*)&sm.hjs[bf][h][aa];
      acc00 = fmaf(v, rcp_native(exp2_native(xi.x + xj.x) + 1.f), acc00);
      acc01 = fmaf(v, rcp_native(exp2_native(xi.y + xj.x) + 1.f), acc01);
      acc10 = fmaf(v, rcp_native(exp2_native(xi.x + xj.y) + 1.f), acc10);
      acc11 = fmaf(v, rcp_native(exp2_native(xi.y + xj.y) + 1.f), acc11);
    }
  }
  const float sv = sm.svas;
  float* pout = P.partials + (size_t)ch * (NB * S * S);
  float2 r0 = {acc00 + sv, acc01 + sv};
  float2 r1 = {acc10 + sv, acc11 + sv};
  *(float2*)&pout[(b * S + a0 + aa) * S + c0 + ca]     = r0;
  *(float2*)&pout[(b * S + a0 + aa + 1) * S + c0 + ca] = r1;
}

// ---------------------------------------------------------------------------
// Phase 3 (one row per wave): combine 6 partials -> logits + top-4; then
// out_type[row,k,l] = fc_b[l] + sum_o tanh(dp[row,o]+hp[b,cand,o])*fc_w[l,o]
__device__ __forceinline__ void topk_row(const Params& P, int row, int lane) {
  const int PP = NB * S * S;
  const float* p = P.partials;
  float v[4];
#pragma unroll
  for (int j = 0; j < 4; ++j) {
    int c = row * S + j * 64 + lane;
    float s0 = p[c]          + p[c + PP];
    float s1 = p[c + 2 * PP] + p[c + 3 * PP];
    float s2 = p[c + 4 * PP] + p[c + 5 * PP];
    v[j] = (s0 + s1) + s2;
    P.logits[c] = v[j];
  }
  int cand[TOPK];
#pragma unroll
  for (int k = 0; k < TOPK; ++k) {
    float bestv = v[0];
    int besti = lane;
#pragma unroll
    for (int j = 1; j < 4; ++j) {
      int c = j * 64 + lane;
      if (v[j] > bestv) { bestv = v[j]; besti = c; }
    }
#pragma unroll
    for (int off = 32; off > 0; off >>= 1) {
      float ov = __shfl_xor(bestv, off);
      int oi = __shfl_xor(besti, off);
      if (ov > bestv || (ov == bestv && oi < besti)) { bestv = ov; besti = oi; }
    }
    int mj = besti >> 6, ml = besti & 63;
#pragma unroll
    for (int j = 0; j < 4; ++j)
      if (lane == ml && j == mj) v[j] = -3.402823466e38f;
    cand[k] = besti;
  }
  const __bf16* dp = P.dpb + (size_t)row * H;
  const int brow0 = (row >> 8) << 8;  // b*S
#pragma unroll
  for (int k = 0; k < TOPK; ++k) {
    const __bf16* hp = P.hpb + (size_t)(brow0 + cand[k]) * H;
    float acc[L] = {};
#pragma unroll
    for (int j = 0; j < 3; ++j) {
      const int o = j * 256 + lane * 4;
      bf16x4 dv = *(const bf16x4*)&dp[o];
      bf16x4 hv = *(const bf16x4*)&hp[o];
      float hd[4];
#pragma unroll
      for (int c = 0; c < 4; ++c)
        hd[c] = fast_tanh((float)dv[c] + (float)hv[c]);
#pragma unroll
      for (int l = 0; l < L; ++l) {
        float4 w = *(const float4*)&P.fc_w[l * H + o];
        acc[l] = fmaf(hd[0], w.x, acc[l]);
        acc[l] = fmaf(hd[1], w.y, acc[l]);
        acc[l] = fmaf(hd[2], w.z, acc[l]);
        acc[l] = fmaf(hd[3], w.w, acc[l]);
      }
    }
#pragma unroll
    for (int l = 0; l < L; ++l)
#pragma unroll
      for (int off = 32; off > 0; off >>= 1) acc[l] += __shfl_xor(acc[l], off);
    if (lane == 0) {
#pragma unroll
      for (int l = 0; l < L; ++l)
        P.out_type[((size_t)row * TOPK + k) * L + l] = acc[l] + P.fc_b[l];
    }
  }
}

// ---------------------------------------------------------------------------
// Fused persistent cooperative kernel: one launch, 3 grid syncs.
__global__ __launch_bounds__(256) void fused_kernel(Params P) {
  __shared__ __align__(16) Smem sm;
  const int bid = blockIdx.x;
  const int t = threadIdx.x;
  cooperative_groups::grid_group grid = cooperative_groups::this_grid();

  cvt_phase(P, bid * 256 + t, GRID * 256);
  __threadfence(); grid.sync();
  mega_phase(P, sm, bid, t);
  __threadfence(); grid.sync();
  biaffine_unit(P, sm, bid, t);
  biaffine_unit(P, sm, bid + GRID, t);
  __threadfence(); grid.sync();
  const int wave = t >> 6, lane = t & 63;
  const int row = bid + GRID * wave;
  if (wave < 2 && row < NB * S) topk_row(P, row, lane);
}

// Fallback path (deterministic, used only if cooperative launch is rejected)
__global__ __launch_bounds__(256) void cvt_k(Params P) {
  cvt_phase(P, blockIdx.x * 256 + threadIdx.x, (int)gridDim.x * 256);
}
__global__ __launch_bounds__(256) void mega_k(Params P) {
  __shared__ __align__(16) Smem sm;
  mega_phase(P, sm, blockIdx.x, threadIdx.x);
}
__global__ __launch_bounds__(256) void biaf_k(Params P) {
  __shared__ __align__(16) Smem sm;
  biaffine_unit(P, sm, blockIdx.x, threadIdx.x);
}
__global__ __launch_bounds__(64) void topk_k(Params P) {
  topk_row(P, blockIdx.x, threadIdx.x);
}

// ---------------------------------------------------------------------------
extern "C" void kernel_launch(void* const* d_in, const int* in_sizes, int n_in,
                              void* d_out, int out_size, void* d_ws, size_t ws_size,
                              hipStream_t stream) {
  Params P;
  P.pooled  = (const float*)d_in[0];
  P.Wa_w    = (const float*)d_in[1];
  P.Wa_b    = (const float*)d_in[2];
  P.Ua_w    = (const float*)d_in[3];
  P.Ua_b    = (const float*)d_in[4];
  P.va      = (const float*)d_in[5];
  P.dense_w = (const float*)d_in[6];
  P.dense_b = (const float*)d_in[7];
  P.fc_w    = (const float*)d_in[8];
  P.fc_b    = (const float*)d_in[9];

  P.logits   = (float*)d_out;               // (4,256,256)
  P.out_type = P.logits + NB * S * S;       // (4,256,4,4)

  // ws layout, 20 MB (known-good). Temporal aliasing: Wh/Wl/Drow live in the
  // partials region (written phase 0, read phase 1, dead before phase 2
  // writes partials -- grid syncs separate them). 6 partial planes = 6 MB.
  float* hij      = (float*)d_ws;                    // [0, 1572864) f
  float* partials = hij + 1572864;                   // [.., +2097152) f (8 MB)
  P.hij      = hij;
  P.partials = partials;
  P.Wh       = (__bf16*)partials;                    // 1179648 bf16 (alias)
  P.Wl       = P.Wh + 1179648;                       // 1179648 bf16 (alias)
  P.Drow     = P.Wl + 1179648;                       // 1179648 bf16 (alias)
  P.dpb      = (__bf16*)(partials + 2097152);        // 786432 bf16
  P.hpb      = P.dpb + 786432;                       // 786432 bf16
  P.Ah       = P.hpb + 786432;                       // 786432 bf16
  P.Al       = P.Ah + 786432;                        // 786432 bf16

  void* args[] = { (void*)&P };
  hipError_t e = hipLaunchCooperativeKernel((const void*)fused_kernel,
                                            dim3(GRID), dim3(256), args, 0, stream);
  if (e != hipSuccess) {
    (void)hipGetLastError();  // clear; deterministic fallback, same math
    cvt_k<<<dim3(3072), 256, 0, stream>>>(P);
    mega_k<<<dim3(GRID), 256, 0, stream>>>(P);
    biaf_k<<<dim3(1536), 256, 0, stream>>>(P);
    topk_k<<<dim3(1024), 64, 0, stream>>>(P);
  }
}

// Round 12
// 151.703 us; speedup vs baseline: 4.5148x; 4.5148x over previous
//
#include <hip/hip_runtime.h>
#include <math.h>

#define H 768
#define S 256
#define NB 4      // batch
#define TOPK 4
#define L 4
#define NH 8      // biaffine h-split chunks (96 h each)

// 2/ln2: tanh(x) = 1 - 2/(2^(C*x)+1)
#define CSCALE 2.8853900817779268f

typedef __bf16 bf16x8 __attribute__((ext_vector_type(8)));
typedef __bf16 bf16x4 __attribute__((ext_vector_type(4)));
typedef float floatx4 __attribute__((ext_vector_type(4)));

__device__ __forceinline__ float exp2_native(float x) {
#if __has_builtin(__builtin_amdgcn_exp2f)
  return __builtin_amdgcn_exp2f(x);
#else
  float r; asm("v_exp_f32 %0, %1" : "=v"(r) : "v"(x)); return r;
#endif
}
__device__ __forceinline__ float rcp_native(float x) {
#if __has_builtin(__builtin_amdgcn_rcpf)
  return __builtin_amdgcn_rcpf(x);
#else
  float r; asm("v_rcp_f32 %0, %1" : "=v"(r) : "v"(x)); return r;
#endif
}
__device__ __forceinline__ float fast_tanh(float x) {
  float cx = fminf(15.f, fmaxf(-15.f, x));
  float e = __expf(cx + cx);
  return __fdividef(e - 1.f, e + 1.f);
}

// ---------------------------------------------------------------------------
// Stage 1 (single GEMM, conversion fused in staging -- r9 body verbatim except
// the hij epilogue now writes TRANSPOSED hijT[col][row] with float4 stores):
// C = pooled(1024x768) @ B^T; B rows 0..1535 = concat(Wa,Ua) hi/lo (3-term
// split -> hijT, CSCALE-scaled); 1536..2303 = dense dep (+dense_b -> dpb);
// 2304..3071 = head (-> hpb). Values bit-identical to rounds 7-10.
__global__ __launch_bounds__(256) void mega_mfma(
    const float* __restrict__ pooled, const float* __restrict__ Wa_w,
    const float* __restrict__ Ua_w, const float* __restrict__ dense_w,
    const float* __restrict__ Wa_b, const float* __restrict__ Ua_b,
    const float* __restrict__ dense_b, float* __restrict__ hijT,
    __bf16* __restrict__ dpb, __bf16* __restrict__ hpb) {
  __shared__ __align__(16) __bf16 Ahs[2][32][40];
  __shared__ __align__(16) __bf16 Als[2][32][40];
  __shared__ __align__(16) __bf16 Bhs[2][128][40];
  __shared__ __align__(16) __bf16 Bls[2][128][40];   // 51.2 KB -> 3 blocks/CU
  const int m0 = blockIdx.x * 32;
  const int g = blockIdx.y;                       // swizzle: even->proj, odd->dense
  const int ng = (g & 1) ? (12 + (g >> 1)) : (g >> 1);
  const int n0 = ng * 128;
  const bool isproj = (ng < 12);
  const int t = threadIdx.x;
  const int arow = t >> 3;
  const int ka = (t & 7) * 4;
  const float* Arow = pooled + (size_t)(m0 + arow) * H;
  const int brow = t >> 1;
  const int kb = (t & 1) * 16;
  const int ncol = n0 + brow;
  const float* Bsrc;
  if (ncol < H)            Bsrc = Wa_w + (size_t)ncol * H;
  else if (ncol < 2 * H)   Bsrc = Ua_w + (size_t)(ncol - H) * H;
  else if (ncol < 3 * H)   Bsrc = dense_w + (size_t)(ncol - 2 * H) * (2 * H);
  else                     Bsrc = dense_w + (size_t)(ncol - 3 * H) * (2 * H) + H;
  const int lane = t & 63;
  const int wave = t >> 6;
  const int wn = wave * 32;
  const int fm = lane & 15;
  const int quad = lane >> 4;
  floatx4 acc[2][2] = {};

  // prologue: prefetch kc = 0
  float4 av = *(const float4*)&Arow[ka];
  float4 w0 = *(const float4*)&Bsrc[kb];
  float4 w1 = *(const float4*)&Bsrc[kb + 4];
  float4 w2 = *(const float4*)&Bsrc[kb + 8];
  float4 w3 = *(const float4*)&Bsrc[kb + 12];

  for (int kc = 0; kc < H; kc += 32) {
    const int bfx = (kc >> 5) & 1;
    {  // A: float4 -> 4 hi + 4 lo (rounding identical to rounds 6-10)
      float f[4] = {av.x, av.y, av.z, av.w};
      union { __bf16 h[4]; ushort4 u; } ah, al;
#pragma unroll
      for (int k = 0; k < 4; ++k) {
        __bf16 hv = (__bf16)f[k];
        ah.h[k] = hv;
        al.h[k] = (__bf16)(f[k] - (float)hv);
      }
      *(ushort4*)&Ahs[bfx][arow][ka] = ah.u;
      *(ushort4*)&Als[bfx][arow][ka] = al.u;
    }
    {  // B: 4 float4 -> 16 hi (+ 16 lo for proj)
      float f[16] = {w0.x, w0.y, w0.z, w0.w, w1.x, w1.y, w1.z, w1.w,
                     w2.x, w2.y, w2.z, w2.w, w3.x, w3.y, w3.z, w3.w};
      bf16x8 bh0, bh1;
#pragma unroll
      for (int k = 0; k < 8; ++k) { bh0[k] = (__bf16)f[k]; bh1[k] = (__bf16)f[k + 8]; }
      *(bf16x8*)&Bhs[bfx][brow][kb] = bh0;
      *(bf16x8*)&Bhs[bfx][brow][kb + 8] = bh1;
      if (isproj) {
        bf16x8 bl0, bl1;
#pragma unroll
        for (int k = 0; k < 8; ++k) {
          bl0[k] = (__bf16)(f[k] - (float)bh0[k]);
          bl1[k] = (__bf16)(f[k + 8] - (float)bh1[k]);
        }
        *(bf16x8*)&Bls[bfx][brow][kb] = bl0;
        *(bf16x8*)&Bls[bfx][brow][kb + 8] = bl1;
      }
    }
    __syncthreads();  // single barrier; buf^1 writers are a full iter behind
    if (kc + 32 < H) {  // prefetch next chunk during MFMA below
      av = *(const float4*)&Arow[kc + 32 + ka];
      w0 = *(const float4*)&Bsrc[kc + 32 + kb];
      w1 = *(const float4*)&Bsrc[kc + 32 + kb + 4];
      w2 = *(const float4*)&Bsrc[kc + 32 + kb + 8];
      w3 = *(const float4*)&Bsrc[kc + 32 + kb + 12];
    }
    bf16x8 afh[2], bfh[2];
#pragma unroll
    for (int i = 0; i < 2; ++i) {
      afh[i] = *(const bf16x8*)&Ahs[bfx][i * 16 + fm][quad * 8];
      bfh[i] = *(const bf16x8*)&Bhs[bfx][wn + i * 16 + fm][quad * 8];
    }
    if (isproj) {
      bf16x8 afl[2], bfl[2];
#pragma unroll
      for (int i = 0; i < 2; ++i) {
        afl[i] = *(const bf16x8*)&Als[bfx][i * 16 + fm][quad * 8];
        bfl[i] = *(const bf16x8*)&Bls[bfx][wn + i * 16 + fm][quad * 8];
      }
#pragma unroll
      for (int i = 0; i < 2; ++i)
#pragma unroll
        for (int j = 0; j < 2; ++j) {  // per-acc order hh,hl,lh == r7-r10
          acc[i][j] = __builtin_amdgcn_mfma_f32_16x16x32_bf16(afh[i], bfh[j], acc[i][j], 0, 0, 0);
          acc[i][j] = __builtin_amdgcn_mfma_f32_16x16x32_bf16(afh[i], bfl[j], acc[i][j], 0, 0, 0);
          acc[i][j] = __builtin_amdgcn_mfma_f32_16x16x32_bf16(afl[i], bfh[j], acc[i][j], 0, 0, 0);
        }
    } else {
#pragma unroll
      for (int i = 0; i < 2; ++i)
#pragma unroll
        for (int j = 0; j < 2; ++j)
          acc[i][j] = __builtin_amdgcn_mfma_f32_16x16x32_bf16(afh[i], bfh[j], acc[i][j], 0, 0, 0);
    }
  }
#pragma unroll
  for (int j = 0; j < 2; ++j) {
    const int col = n0 + wn + j * 16 + fm;
    if (col < 2 * H) {          // hijT[col][row]: float4 over 4 consecutive rows
      const float bias = (col < H) ? Wa_b[col] : Ua_b[col - H];
#pragma unroll
      for (int i = 0; i < 2; ++i) {
        float4 o;
        o.x = CSCALE * (acc[i][j][0] + bias);
        o.y = CSCALE * (acc[i][j][1] + bias);
        o.z = CSCALE * (acc[i][j][2] + bias);
        o.w = CSCALE * (acc[i][j][3] + bias);
        *(float4*)&hijT[(size_t)col * 1024 + m0 + i * 16 + quad * 4] = o;
      }
    } else if (col < 3 * H) {   // dp: + dense_b, bf16 (row-major, unchanged)
      const int o = col - 2 * H;
      const float bias = dense_b[o];
#pragma unroll
      for (int i = 0; i < 2; ++i)
#pragma unroll
        for (int rg = 0; rg < 4; ++rg) {
          const int row = m0 + i * 16 + quad * 4 + rg;
          dpb[(size_t)row * H + o] = (__bf16)(acc[i][j][rg] + bias);
        }
    } else {                    // hp: raw, bf16
      const int o = col - 3 * H;
#pragma unroll
      for (int i = 0; i < 2; ++i)
#pragma unroll
        for (int rg = 0; rg < 4; ++rg) {
          const int row = m0 + i * 16 + quad * 4 + rg;
          hpb[(size_t)row * H + o] = (__bf16)acc[i][j][rg];
        }
    }
  }
}

// ---------------------------------------------------------------------------
// Stage 2: partial[ch][b,a,c] = Sva_ch + sum_{h in ch} (-2 va[h]) * rcp(2^(xi+xj)+1)
// hij now transposed -> global loads fully coalesced (16 lanes = 64 contiguous
// bytes) instead of 4B-per-lane scatter at stride 6KB. Math/order unchanged.
__global__ __launch_bounds__(256) void biaffine4(
    const float* __restrict__ hijT, const float* __restrict__ va,
    float* __restrict__ partials) {
  __shared__ __align__(16) float his[2][16][34];
  __shared__ __align__(16) float hjs[2][16][34];
  __shared__ __align__(16) float vas2[96];
  __shared__ float svas;
  const int z = blockIdx.z;
  const int b = z >> 3;
  const int ch = z & 7;
  const int hc0 = ch * 96;
  const int a0 = blockIdx.y * 32;
  const int c0 = blockIdx.x * 32;
  const int t = threadIdx.x;
  if (t < 96) vas2[t] = -2.f * va[hc0 + t];
  __syncthreads();
  if (t < 64) {
    float s = vas2[t] + ((t < 32) ? vas2[t + 64] : 0.f);
#pragma unroll
    for (int off = 32; off > 0; off >>= 1) s += __shfl_xor(s, off);
    if (t == 0) svas = -0.5f * s;
  }
  // loaders: lh = h-index (slow), lr = row-index (fast, coalesced)
  const int lh = t >> 4;       // 0..15
  const int lr = t & 15;       // 0..15
  const int ca = (t & 15) * 2;
  const int aa = (t >> 4) * 2;
  const float* bi = hijT + (size_t)(hc0 + lh) * 1024 + b * S + c0 + lr;
  const float* bj = hijT + (size_t)(768 + hc0 + lh) * 1024 + b * S + a0 + lr;
  float acc00 = 0.f, acc01 = 0.f, acc10 = 0.f, acc11 = 0.f;

  float pi0 = bi[0], pi1 = bi[16], pj0 = bj[0], pj1 = bj[16];
  for (int hr = 0; hr < 96; hr += 16) {
    const int bf = (hr >> 4) & 1;
    his[bf][lh][lr]      = pi0;
    his[bf][lh][lr + 16] = pi1;
    hjs[bf][lh][lr]      = pj0;
    hjs[bf][lh][lr + 16] = pj1;
    __syncthreads();
    if (hr + 16 < 96) {
      const size_t off = (size_t)(hr + 16) * 1024;
      pi0 = bi[off]; pi1 = bi[off + 16];
      pj0 = bj[off]; pj1 = bj[off + 16];
    }
    float vreg[16];
    *(float4*)&vreg[0]  = *(const float4*)&vas2[hr + 0];
    *(float4*)&vreg[4]  = *(const float4*)&vas2[hr + 4];
    *(float4*)&vreg[8]  = *(const float4*)&vas2[hr + 8];
    *(float4*)&vreg[12] = *(const float4*)&vas2[hr + 12];
#pragma unroll
    for (int h = 0; h < 16; ++h) {
      float v = vreg[h];
      float2 xi = *(const float2*)&his[bf][h][ca];
      float2 xj = *(const float2*)&hjs[bf][h][aa];
      acc00 = fmaf(v, rcp_native(exp2_native(xi.x + xj.x) + 1.f), acc00);
      acc01 = fmaf(v, rcp_native(exp2_native(xi.y + xj.x) + 1.f), acc01);
      acc10 = fmaf(v, rcp_native(exp2_native(xi.x + xj.y) + 1.f), acc10);
      acc11 = fmaf(v, rcp_native(exp2_native(xi.y + xj.y) + 1.f), acc11);
    }
  }
  const float sv = svas;
  float* pout = partials + (size_t)ch * (NB * S * S);
  float2 r0 = {acc00 + sv, acc01 + sv};
  float2 r1 = {acc10 + sv, acc11 + sv};
  *(float2*)&pout[(b * S + a0 + aa) * S + c0 + ca]     = r0;
  *(float2*)&pout[(b * S + a0 + aa + 1) * S + c0 + ca] = r1;
}

// ---------------------------------------------------------------------------
// Stage 3 (256-thread blocks): wave 0 combines 8 partials -> logits + top-4
// (fp order identical to r9); candidates via LDS; then each of the 4 waves
// computes one candidate's type logits (16 waves/CU vs r9's 4 -- the fc
// latency chains were exposed at 64-thread blocks).
__global__ __launch_bounds__(256) void topk_final(
    const float* __restrict__ partials, const __bf16* __restrict__ dpb,
    const __bf16* __restrict__ hpb, const float* __restrict__ fc_w,
    const float* __restrict__ fc_b, float* __restrict__ logits,
    float* __restrict__ out_type) {
  __shared__ int scand[TOPK];
  const int row = blockIdx.x;  // b*S + a
  const int t = threadIdx.x;
  const int wave = t >> 6, lane = t & 63;
  if (wave == 0) {
    const int P = NB * S * S;
    float v[4];
#pragma unroll
    for (int j = 0; j < 4; ++j) {
      int c = row * S + j * 64 + lane;
      float s0 = partials[c]         + partials[c + P];
      float s1 = partials[c + 2 * P] + partials[c + 3 * P];
      float s2 = partials[c + 4 * P] + partials[c + 5 * P];
      float s3 = partials[c + 6 * P] + partials[c + 7 * P];
      v[j] = (s0 + s1) + (s2 + s3);
      logits[c] = v[j];
    }
#pragma unroll
    for (int k = 0; k < TOPK; ++k) {
      float bestv = v[0];
      int besti = lane;
#pragma unroll
      for (int j = 1; j < 4; ++j) {
        int c = j * 64 + lane;
        if (v[j] > bestv) { bestv = v[j]; besti = c; }
      }
#pragma unroll
      for (int off = 32; off > 0; off >>= 1) {
        float ov = __shfl_xor(bestv, off);
        int oi = __shfl_xor(besti, off);
        if (ov > bestv || (ov == bestv && oi < besti)) { bestv = ov; besti = oi; }
      }
      int mj = besti >> 6, ml = besti & 63;
#pragma unroll
      for (int j = 0; j < 4; ++j)
        if (lane == ml && j == mj) v[j] = -3.402823466e38f;
      if (lane == 0) scand[k] = besti;
    }
  }
  __syncthreads();
  // each wave: one candidate
  const int k = wave;
  const __bf16* dp = dpb + (size_t)row * H;
  const int brow0 = (row >> 8) << 8;  // b*S
  const __bf16* hp = hpb + (size_t)(brow0 + scand[k]) * H;
  float acc[L] = {};
#pragma unroll
  for (int j = 0; j < 3; ++j) {
    const int o = j * 256 + lane * 4;
    bf16x4 dv = *(const bf16x4*)&dp[o];
    bf16x4 hv = *(const bf16x4*)&hp[o];
    float hd[4];
#pragma unroll
    for (int c = 0; c < 4; ++c)
      hd[c] = fast_tanh((float)dv[c] + (float)hv[c]);
#pragma unroll
    for (int l = 0; l < L; ++l) {
      float4 w = *(const float4*)&fc_w[l * H + o];
      acc[l] = fmaf(hd[0], w.x, acc[l]);
      acc[l] = fmaf(hd[1], w.y, acc[l]);
      acc[l] = fmaf(hd[2], w.z, acc[l]);
      acc[l] = fmaf(hd[3], w.w, acc[l]);
    }
  }
#pragma unroll
  for (int l = 0; l < L; ++l)
#pragma unroll
    for (int off = 32; off > 0; off >>= 1) acc[l] += __shfl_xor(acc[l], off);
  if (lane == 0) {
#pragma unroll
    for (int l = 0; l < L; ++l)
      out_type[((size_t)row * TOPK + k) * L + l] = acc[l] + fc_b[l];
  }
}

// ---------------------------------------------------------------------------
extern "C" void kernel_launch(void* const* d_in, const int* in_sizes, int n_in,
                              void* d_out, int out_size, void* d_ws, size_t ws_size,
                              hipStream_t stream) {
  const float* pooled  = (const float*)d_in[0];
  const float* Wa_w    = (const float*)d_in[1];
  const float* Wa_b    = (const float*)d_in[2];
  const float* Ua_w    = (const float*)d_in[3];
  const float* Ua_b    = (const float*)d_in[4];
  const float* va_w    = (const float*)d_in[5];
  const float* dense_w = (const float*)d_in[6];
  const float* dense_b = (const float*)d_in[7];
  const float* fc_w    = (const float*)d_in[8];
  const float* fc_b    = (const float*)d_in[9];

  float* logits   = (float*)d_out;            // (4,256,256)
  float* out_type = logits + NB * S * S;      // (4,256,4,4)

  // ws layout, 17.1 MB. mega writes hijT/dpb/hpb; biaffine reads hijT,
  // writes partials; topk_final reads partials/dpb/hpb.
  float*  hijT     = (float*)d_ws;                   // 1536 x 1024 f
  float*  partials = hijT + 1572864;                 // 2097152 f (8 planes)
  __bf16* dpb      = (__bf16*)(partials + 2097152);  // 786432 bf16
  __bf16* hpb      = dpb + 786432;                   // 786432 bf16

  mega_mfma<<<dim3(32, 24), 256, 0, stream>>>(pooled, Wa_w, Ua_w, dense_w,
                                              Wa_b, Ua_b, dense_b,
                                              hijT, dpb, hpb);
  biaffine4<<<dim3(8, 8, NB * NH), 256, 0, stream>>>(hijT, va_w, partials);
  topk_final<<<dim3(1024), 256, 0, stream>>>(partials, dpb, hpb, fc_w, fc_b,
                                             logits, out_type);
}

// Round 13
// 150.704 us; speedup vs baseline: 4.5447x; 1.0066x over previous
//
#include <hip/hip_runtime.h>
#include <math.h>

#define H 768
#define S 256
#define NB 4      // batch
#define TOPK 4
#define L 4
#define NH 4      // biaffine h-split chunks (192 h each; r5-validated)

// 2/ln2: tanh(x) = 1 - 2/(2^(C*x)+1)
#define CSCALE 2.8853900817779268f

typedef __bf16 bf16x8 __attribute__((ext_vector_type(8)));
typedef __bf16 bf16x4 __attribute__((ext_vector_type(4)));
typedef float floatx4 __attribute__((ext_vector_type(4)));
typedef float floatx2 __attribute__((ext_vector_type(2)));

__device__ __forceinline__ float exp2_native(float x) {
#if __has_builtin(__builtin_amdgcn_exp2f)
  return __builtin_amdgcn_exp2f(x);
#else
  float r; asm("v_exp_f32 %0, %1" : "=v"(r) : "v"(x)); return r;
#endif
}
__device__ __forceinline__ float rcp_native(float x) {
#if __has_builtin(__builtin_amdgcn_rcpf)
  return __builtin_amdgcn_rcpf(x);
#else
  float r; asm("v_rcp_f32 %0, %1" : "=v"(r) : "v"(x)); return r;
#endif
}
__device__ __forceinline__ floatx2 fma2(floatx2 a, floatx2 b, floatx2 c) {
#if __has_builtin(__builtin_elementwise_fma)
  return __builtin_elementwise_fma(a, b, c);
#else
  floatx2 r; r.x = fmaf(a.x, b.x, c.x); r.y = fmaf(a.y, b.y, c.y); return r;
#endif
}
__device__ __forceinline__ float fast_tanh(float x) {
  float cx = fminf(15.f, fmaxf(-15.f, x));
  float e = __expf(cx + cx);
  return __fdividef(e - 1.f, e + 1.f);
}

// ---------------------------------------------------------------------------
// Stage 1 (single GEMM, conversion fused, 64x64 tiles): C = pooled @ B^T.
// B rows 0..1535 = concat(Wa,Ua) hi/lo (3-term split -> hijT, CSCALE-scaled);
// 1536..2303 = dense dep (+dense_b -> dpb); 2304..3071 = head (-> hpb).
// 64x64 tile (r13): per-block global traffic 392 KB vs r12's 491 KB; B
// re-reads 16x vs 32x. Grid 16x48 = 768 = 3 blocks/CU at 41 KB LDS.
// K order + per-acc MFMA term order unchanged -> outputs bit-identical.
__global__ __launch_bounds__(256) void mega_mfma(
    const float* __restrict__ pooled, const float* __restrict__ Wa_w,
    const float* __restrict__ Ua_w, const float* __restrict__ dense_w,
    const float* __restrict__ Wa_b, const float* __restrict__ Ua_b,
    const float* __restrict__ dense_b, float* __restrict__ hijT,
    __bf16* __restrict__ dpb, __bf16* __restrict__ hpb) {
  __shared__ __align__(16) __bf16 Ahs[2][64][40];
  __shared__ __align__(16) __bf16 Als[2][64][40];
  __shared__ __align__(16) __bf16 Bhs[2][64][40];
  __shared__ __align__(16) __bf16 Bls[2][64][40];   // 40.96 KB -> 3 blocks/CU
  const int m0 = blockIdx.x * 64;
  const int g = blockIdx.y;                  // swizzle: even->proj, odd->dense
  const int ng = (g & 1) ? (24 + (g >> 1)) : (g >> 1);   // 0..47
  const int n0 = ng * 64;
  const bool isproj = (ng < 24);
  const int t = threadIdx.x;
  // A staging: 64 rows x 32 k; thread: row t>>2, 8 floats at (t&3)*8
  const int arow = t >> 2;
  const int ka = (t & 3) * 8;
  const float* Arow = pooled + (size_t)(m0 + arow) * H;
  // B staging: 64 rows x 32 k; same pattern
  const int brow = t >> 2;
  const int kb = (t & 3) * 8;
  const int ncol = n0 + brow;
  const float* Bsrc;
  if (ncol < H)            Bsrc = Wa_w + (size_t)ncol * H;
  else if (ncol < 2 * H)   Bsrc = Ua_w + (size_t)(ncol - H) * H;
  else if (ncol < 3 * H)   Bsrc = dense_w + (size_t)(ncol - 2 * H) * (2 * H);
  else                     Bsrc = dense_w + (size_t)(ncol - 3 * H) * (2 * H) + H;
  const int lane = t & 63;
  const int wave = t >> 6;
  const int wm = (wave & 1) * 32;
  const int wn = (wave >> 1) * 32;
  const int fm = lane & 15;
  const int quad = lane >> 4;
  floatx4 acc[2][2] = {};

  // prologue: prefetch kc = 0
  float4 av0 = *(const float4*)&Arow[ka];
  float4 av1 = *(const float4*)&Arow[ka + 4];
  float4 w0 = *(const float4*)&Bsrc[kb];
  float4 w1 = *(const float4*)&Bsrc[kb + 4];

  for (int kc = 0; kc < H; kc += 32) {
    const int bfx = (kc >> 5) & 1;
    {  // A: 8 floats -> 8 hi + 8 lo (elementwise rounding, identical to r6-r12)
      float f[8] = {av0.x, av0.y, av0.z, av0.w, av1.x, av1.y, av1.z, av1.w};
      bf16x8 ah, al;
#pragma unroll
      for (int k = 0; k < 8; ++k) {
        ah[k] = (__bf16)f[k];
        al[k] = (__bf16)(f[k] - (float)ah[k]);
      }
      *(bf16x8*)&Ahs[bfx][arow][ka] = ah;
      *(bf16x8*)&Als[bfx][arow][ka] = al;
    }
    {  // B: 8 floats -> 8 hi (+ 8 lo for proj)
      float f[8] = {w0.x, w0.y, w0.z, w0.w, w1.x, w1.y, w1.z, w1.w};
      bf16x8 bh;
#pragma unroll
      for (int k = 0; k < 8; ++k) bh[k] = (__bf16)f[k];
      *(bf16x8*)&Bhs[bfx][brow][kb] = bh;
      if (isproj) {
        bf16x8 bl;
#pragma unroll
        for (int k = 0; k < 8; ++k) bl[k] = (__bf16)(f[k] - (float)bh[k]);
        *(bf16x8*)&Bls[bfx][brow][kb] = bl;
      }
    }
    __syncthreads();  // single barrier; buf^1 writers are a full iter behind
    if (kc + 32 < H) {  // prefetch next chunk during MFMA below
      av0 = *(const float4*)&Arow[kc + 32 + ka];
      av1 = *(const float4*)&Arow[kc + 32 + ka + 4];
      w0 = *(const float4*)&Bsrc[kc + 32 + kb];
      w1 = *(const float4*)&Bsrc[kc + 32 + kb + 4];
    }
    bf16x8 afh[2], bfh[2];
#pragma unroll
    for (int i = 0; i < 2; ++i) {
      afh[i] = *(const bf16x8*)&Ahs[bfx][wm + i * 16 + fm][quad * 8];
      bfh[i] = *(const bf16x8*)&Bhs[bfx][wn + i * 16 + fm][quad * 8];
    }
    if (isproj) {
      bf16x8 afl[2], bfl[2];
#pragma unroll
      for (int i = 0; i < 2; ++i) {
        afl[i] = *(const bf16x8*)&Als[bfx][wm + i * 16 + fm][quad * 8];
        bfl[i] = *(const bf16x8*)&Bls[bfx][wn + i * 16 + fm][quad * 8];
      }
#pragma unroll
      for (int i = 0; i < 2; ++i)
#pragma unroll
        for (int j = 0; j < 2; ++j) {  // per-acc order hh,hl,lh == r7-r12
          acc[i][j] = __builtin_amdgcn_mfma_f32_16x16x32_bf16(afh[i], bfh[j], acc[i][j], 0, 0, 0);
          acc[i][j] = __builtin_amdgcn_mfma_f32_16x16x32_bf16(afh[i], bfl[j], acc[i][j], 0, 0, 0);
          acc[i][j] = __builtin_amdgcn_mfma_f32_16x16x32_bf16(afl[i], bfh[j], acc[i][j], 0, 0, 0);
        }
    } else {
#pragma unroll
      for (int i = 0; i < 2; ++i)
#pragma unroll
        for (int j = 0; j < 2; ++j)
          acc[i][j] = __builtin_amdgcn_mfma_f32_16x16x32_bf16(afh[i], bfh[j], acc[i][j], 0, 0, 0);
    }
  }
#pragma unroll
  for (int j = 0; j < 2; ++j) {
    const int col = n0 + wn + j * 16 + fm;
    if (col < 2 * H) {          // hijT[col][row]: float4 over 4 consecutive rows
      const float bias = (col < H) ? Wa_b[col] : Ua_b[col - H];
#pragma unroll
      for (int i = 0; i < 2; ++i) {
        float4 o;
        o.x = CSCALE * (acc[i][j][0] + bias);
        o.y = CSCALE * (acc[i][j][1] + bias);
        o.z = CSCALE * (acc[i][j][2] + bias);
        o.w = CSCALE * (acc[i][j][3] + bias);
        *(float4*)&hijT[(size_t)col * 1024 + m0 + wm + i * 16 + quad * 4] = o;
      }
    } else if (col < 3 * H) {   // dp: + dense_b, bf16
      const int o = col - 2 * H;
      const float bias = dense_b[o];
#pragma unroll
      for (int i = 0; i < 2; ++i)
#pragma unroll
        for (int rg = 0; rg < 4; ++rg) {
          const int row = m0 + wm + i * 16 + quad * 4 + rg;
          dpb[(size_t)row * H + o] = (__bf16)(acc[i][j][rg] + bias);
        }
    } else {                    // hp: raw, bf16
      const int o = col - 3 * H;
#pragma unroll
      for (int i = 0; i < 2; ++i)
#pragma unroll
        for (int rg = 0; rg < 4; ++rg) {
          const int row = m0 + wm + i * 16 + quad * 4 + rg;
          hpb[(size_t)row * H + o] = (__bf16)acc[i][j][rg];
        }
    }
  }
}

// ---------------------------------------------------------------------------
// Stage 2: partial[ch][b,a,c] = Sva_ch + sum_{192h} (-2 va[h]) * rcp(2^(xi+xj)+1)
// Coalesced hijT loads (r12); adds/fmas in packed fp32 (v_pk_*) -- per-lane
// IEEE ops identical -> logits bit-identical. NH=4 (r5-validated grouping).
__global__ __launch_bounds__(256) void biaffine4(
    const float* __restrict__ hijT, const float* __restrict__ va,
    float* __restrict__ partials) {
  __shared__ __align__(16) float his[2][16][34];
  __shared__ __align__(16) float hjs[2][16][34];
  __shared__ __align__(16) float vas2[192];
  __shared__ float svas;
  const int z = blockIdx.z;
  const int b = z >> 2;
  const int ch = z & 3;
  const int hc0 = ch * 192;
  const int a0 = blockIdx.y * 32;
  const int c0 = blockIdx.x * 32;
  const int t = threadIdx.x;
  if (t < 192) vas2[t] = -2.f * va[hc0 + t];
  __syncthreads();
  if (t < 64) {
    float s = vas2[t] + vas2[t + 64] + vas2[t + 128];
#pragma unroll
    for (int off = 32; off > 0; off >>= 1) s += __shfl_xor(s, off);
    if (t == 0) svas = -0.5f * s;
  }
  const int lh = t >> 4;       // h-index (slow)
  const int lr = t & 15;       // row-index (fast, coalesced)
  const int ca = (t & 15) * 2;
  const int aa = (t >> 4) * 2;
  const float* bi = hijT + (size_t)(hc0 + lh) * 1024 + b * S + c0 + lr;
  const float* bj = hijT + (size_t)(768 + hc0 + lh) * 1024 + b * S + a0 + lr;
  floatx2 acc0 = {0.f, 0.f}, acc1 = {0.f, 0.f};
  const floatx2 one = {1.f, 1.f};

  float pi0 = bi[0], pi1 = bi[16], pj0 = bj[0], pj1 = bj[16];
  for (int hr = 0; hr < 192; hr += 16) {
    const int bf = (hr >> 4) & 1;
    his[bf][lh][lr]      = pi0;
    his[bf][lh][lr + 16] = pi1;
    hjs[bf][lh][lr]      = pj0;
    hjs[bf][lh][lr + 16] = pj1;
    __syncthreads();
    if (hr + 16 < 192) {
      const size_t off = (size_t)(hr + 16) * 1024;
      pi0 = bi[off]; pi1 = bi[off + 16];
      pj0 = bj[off]; pj1 = bj[off + 16];
    }
    float vreg[16];
    *(float4*)&vreg[0]  = *(const float4*)&vas2[hr + 0];
    *(float4*)&vreg[4]  = *(const float4*)&vas2[hr + 4];
    *(float4*)&vreg[8]  = *(const float4*)&vas2[hr + 8];
    *(float4*)&vreg[12] = *(const float4*)&vas2[hr + 12];
#pragma unroll
    for (int h = 0; h < 16; ++h) {
      const float v = vreg[h];
      const floatx2 vv = {v, v};
      floatx2 xi = *(const floatx2*)&his[bf][h][ca];
      floatx2 xj = *(const floatx2*)&hjs[bf][h][aa];
      floatx2 t0 = xi + (floatx2){xj.x, xj.x};   // (xi.x+xj.x, xi.y+xj.x)
      floatx2 t1 = xi + (floatx2){xj.y, xj.y};   // (xi.x+xj.y, xi.y+xj.y)
      floatx2 e0 = {exp2_native(t0.x), exp2_native(t0.y)};
      floatx2 e1 = {exp2_native(t1.x), exp2_native(t1.y)};
      e0 = e0 + one;
      e1 = e1 + one;
      floatx2 r0 = {rcp_native(e0.x), rcp_native(e0.y)};
      floatx2 r1 = {rcp_native(e1.x), rcp_native(e1.y)};
      acc0 = fma2(vv, r0, acc0);
      acc1 = fma2(vv, r1, acc1);
    }
  }
  const float sv = svas;
  float* pout = partials + (size_t)ch * (NB * S * S);
  float2 r0 = {acc0.x + sv, acc0.y + sv};
  float2 r1 = {acc1.x + sv, acc1.y + sv};
  *(float2*)&pout[(b * S + a0 + aa) * S + c0 + ca]     = r0;
  *(float2*)&pout[(b * S + a0 + aa + 1) * S + c0 + ca] = r1;
}

// ---------------------------------------------------------------------------
// Stage 3 (256 threads): wave 0 combines 4 partials -> logits + top-4;
// candidates via LDS; each wave computes one candidate's type logits.
__global__ __launch_bounds__(256) void topk_final(
    const float* __restrict__ partials, const __bf16* __restrict__ dpb,
    const __bf16* __restrict__ hpb, const float* __restrict__ fc_w,
    const float* __restrict__ fc_b, float* __restrict__ logits,
    float* __restrict__ out_type) {
  __shared__ int scand[TOPK];
  const int row = blockIdx.x;  // b*S + a
  const int t = threadIdx.x;
  const int wave = t >> 6, lane = t & 63;
  if (wave == 0) {
    const int P = NB * S * S;
    float v[4];
#pragma unroll
    for (int j = 0; j < 4; ++j) {
      int c = row * S + j * 64 + lane;
      v[j] = (partials[c] + partials[c + P]) +
             (partials[c + 2 * P] + partials[c + 3 * P]);
      logits[c] = v[j];
    }
#pragma unroll
    for (int k = 0; k < TOPK; ++k) {
      float bestv = v[0];
      int besti = lane;
#pragma unroll
      for (int j = 1; j < 4; ++j) {
        int c = j * 64 + lane;
        if (v[j] > bestv) { bestv = v[j]; besti = c; }
      }
#pragma unroll
      for (int off = 32; off > 0; off >>= 1) {
        float ov = __shfl_xor(bestv, off);
        int oi = __shfl_xor(besti, off);
        if (ov > bestv || (ov == bestv && oi < besti)) { bestv = ov; besti = oi; }
      }
      int mj = besti >> 6, ml = besti & 63;
#pragma unroll
      for (int j = 0; j < 4; ++j)
        if (lane == ml && j == mj) v[j] = -3.402823466e38f;
      if (lane == 0) scand[k] = besti;
    }
  }
  __syncthreads();
  const int k = wave;
  const __bf16* dp = dpb + (size_t)row * H;
  const int brow0 = (row >> 8) << 8;  // b*S
  const __bf16* hp = hpb + (size_t)(brow0 + scand[k]) * H;
  float acc[L] = {};
#pragma unroll
  for (int j = 0; j < 3; ++j) {
    const int o = j * 256 + lane * 4;
    bf16x4 dv = *(const bf16x4*)&dp[o];
    bf16x4 hv = *(const bf16x4*)&hp[o];
    float hd[4];
#pragma unroll
    for (int c = 0; c < 4; ++c)
      hd[c] = fast_tanh((float)dv[c] + (float)hv[c]);
#pragma unroll
    for (int l = 0; l < L; ++l) {
      float4 w = *(const float4*)&fc_w[l * H + o];
      acc[l] = fmaf(hd[0], w.x, acc[l]);
      acc[l] = fmaf(hd[1], w.y, acc[l]);
      acc[l] = fmaf(hd[2], w.z, acc[l]);
      acc[l] = fmaf(hd[3], w.w, acc[l]);
    }
  }
#pragma unroll
  for (int l = 0; l < L; ++l)
#pragma unroll
    for (int off = 32; off > 0; off >>= 1) acc[l] += __shfl_xor(acc[l], off);
  if (lane == 0) {
#pragma unroll
    for (int l = 0; l < L; ++l)
      out_type[((size_t)row * TOPK + k) * L + l] = acc[l] + fc_b[l];
  }
}

// ---------------------------------------------------------------------------
extern "C" void kernel_launch(void* const* d_in, const int* in_sizes, int n_in,
                              void* d_out, int out_size, void* d_ws, size_t ws_size,
                              hipStream_t stream) {
  const float* pooled  = (const float*)d_in[0];
  const float* Wa_w    = (const float*)d_in[1];
  const float* Wa_b    = (const float*)d_in[2];
  const float* Ua_w    = (const float*)d_in[3];
  const float* Ua_b    = (const float*)d_in[4];
  const float* va_w    = (const float*)d_in[5];
  const float* dense_w = (const float*)d_in[6];
  const float* dense_b = (const float*)d_in[7];
  const float* fc_w    = (const float*)d_in[8];
  const float* fc_b    = (const float*)d_in[9];

  float* logits   = (float*)d_out;            // (4,256,256)
  float* out_type = logits + NB * S * S;      // (4,256,4,4)

  // ws layout, 13.1 MB. mega writes hijT/dpb/hpb; biaffine reads hijT,
  // writes partials (4 planes); topk_final reads partials/dpb/hpb.
  float*  hijT     = (float*)d_ws;                   // 1536 x 1024 f (6 MB)
  float*  partials = hijT + 1572864;                 // 1048576 f (4 MB)
  __bf16* dpb      = (__bf16*)(partials + 1048576);  // 786432 bf16
  __bf16* hpb      = dpb + 786432;                   // 786432 bf16

  mega_mfma<<<dim3(16, 48), 256, 0, stream>>>(pooled, Wa_w, Ua_w, dense_w,
                                              Wa_b, Ua_b, dense_b,
                                              hijT, dpb, hpb);
  biaffine4<<<dim3(8, 8, NB * NH), 256, 0, stream>>>(hijT, va_w, partials);
  topk_final<<<dim3(1024), 256, 0, stream>>>(partials, dpb, hpb, fc_w, fc_b,
                                             logits, out_type);
}

// Round 14
// 149.526 us; speedup vs baseline: 4.5805x; 1.0079x over previous
//
#include <hip/hip_runtime.h>
#include <math.h>

#define H 768
#define S 256
#define NB 4      // batch
#define TOPK 4
#define L 4
#define NH 8      // biaffine h-split chunks (96 h each): 2048 blocks = 8/CU

// 2/ln2: tanh(x) = 1 - 2/(2^(C*x)+1)
#define CSCALE 2.8853900817779268f

typedef __bf16 bf16x8 __attribute__((ext_vector_type(8)));
typedef __bf16 bf16x4 __attribute__((ext_vector_type(4)));
typedef float floatx4 __attribute__((ext_vector_type(4)));
typedef float floatx2 __attribute__((ext_vector_type(2)));

__device__ __forceinline__ float exp2_native(float x) {
#if __has_builtin(__builtin_amdgcn_exp2f)
  return __builtin_amdgcn_exp2f(x);
#else
  float r; asm("v_exp_f32 %0, %1" : "=v"(r) : "v"(x)); return r;
#endif
}
__device__ __forceinline__ float rcp_native(float x) {
#if __has_builtin(__builtin_amdgcn_rcpf)
  return __builtin_amdgcn_rcpf(x);
#else
  float r; asm("v_rcp_f32 %0, %1" : "=v"(r) : "v"(x)); return r;
#endif
}
__device__ __forceinline__ floatx2 fma2(floatx2 a, floatx2 b, floatx2 c) {
#if __has_builtin(__builtin_elementwise_fma)
  return __builtin_elementwise_fma(a, b, c);
#else
  floatx2 r; r.x = fmaf(a.x, b.x, c.x); r.y = fmaf(a.y, b.y, c.y); return r;
#endif
}
__device__ __forceinline__ float fast_tanh(float x) {
  float cx = fminf(15.f, fmaxf(-15.f, x));
  float e = __expf(cx + cx);
  return __fdividef(e - 1.f, e + 1.f);
}

// ---------------------------------------------------------------------------
// Stage 1 (single GEMM, conversion fused, 64x64 tiles -- r13 body verbatim):
// C = pooled @ B^T. B rows 0..1535 = concat(Wa,Ua) hi/lo (3-term -> hijT,
// CSCALE-scaled); 1536..2303 = dense dep (+dense_b -> dpb); 2304..3071 = head.
__global__ __launch_bounds__(256) void mega_mfma(
    const float* __restrict__ pooled, const float* __restrict__ Wa_w,
    const float* __restrict__ Ua_w, const float* __restrict__ dense_w,
    const float* __restrict__ Wa_b, const float* __restrict__ Ua_b,
    const float* __restrict__ dense_b, float* __restrict__ hijT,
    __bf16* __restrict__ dpb, __bf16* __restrict__ hpb) {
  __shared__ __align__(16) __bf16 Ahs[2][64][40];
  __shared__ __align__(16) __bf16 Als[2][64][40];
  __shared__ __align__(16) __bf16 Bhs[2][64][40];
  __shared__ __align__(16) __bf16 Bls[2][64][40];   // 40.96 KB -> 3 blocks/CU
  const int m0 = blockIdx.x * 64;
  const int g = blockIdx.y;                  // swizzle: even->proj, odd->dense
  const int ng = (g & 1) ? (24 + (g >> 1)) : (g >> 1);   // 0..47
  const int n0 = ng * 64;
  const bool isproj = (ng < 24);
  const int t = threadIdx.x;
  const int arow = t >> 2;
  const int ka = (t & 3) * 8;
  const float* Arow = pooled + (size_t)(m0 + arow) * H;
  const int brow = t >> 2;
  const int kb = (t & 3) * 8;
  const int ncol = n0 + brow;
  const float* Bsrc;
  if (ncol < H)            Bsrc = Wa_w + (size_t)ncol * H;
  else if (ncol < 2 * H)   Bsrc = Ua_w + (size_t)(ncol - H) * H;
  else if (ncol < 3 * H)   Bsrc = dense_w + (size_t)(ncol - 2 * H) * (2 * H);
  else                     Bsrc = dense_w + (size_t)(ncol - 3 * H) * (2 * H) + H;
  const int lane = t & 63;
  const int wave = t >> 6;
  const int wm = (wave & 1) * 32;
  const int wn = (wave >> 1) * 32;
  const int fm = lane & 15;
  const int quad = lane >> 4;
  floatx4 acc[2][2] = {};

  float4 av0 = *(const float4*)&Arow[ka];
  float4 av1 = *(const float4*)&Arow[ka + 4];
  float4 w0 = *(const float4*)&Bsrc[kb];
  float4 w1 = *(const float4*)&Bsrc[kb + 4];

  for (int kc = 0; kc < H; kc += 32) {
    const int bfx = (kc >> 5) & 1;
    {  // A: 8 floats -> 8 hi + 8 lo (rounding identical to r6-r13)
      float f[8] = {av0.x, av0.y, av0.z, av0.w, av1.x, av1.y, av1.z, av1.w};
      bf16x8 ah, al;
#pragma unroll
      for (int k = 0; k < 8; ++k) {
        ah[k] = (__bf16)f[k];
        al[k] = (__bf16)(f[k] - (float)ah[k]);
      }
      *(bf16x8*)&Ahs[bfx][arow][ka] = ah;
      *(bf16x8*)&Als[bfx][arow][ka] = al;
    }
    {  // B: 8 floats -> 8 hi (+ 8 lo for proj)
      float f[8] = {w0.x, w0.y, w0.z, w0.w, w1.x, w1.y, w1.z, w1.w};
      bf16x8 bh;
#pragma unroll
      for (int k = 0; k < 8; ++k) bh[k] = (__bf16)f[k];
      *(bf16x8*)&Bhs[bfx][brow][kb] = bh;
      if (isproj) {
        bf16x8 bl;
#pragma unroll
        for (int k = 0; k < 8; ++k) bl[k] = (__bf16)(f[k] - (float)bh[k]);
        *(bf16x8*)&Bls[bfx][brow][kb] = bl;
      }
    }
    __syncthreads();
    if (kc + 32 < H) {
      av0 = *(const float4*)&Arow[kc + 32 + ka];
      av1 = *(const float4*)&Arow[kc + 32 + ka + 4];
      w0 = *(const float4*)&Bsrc[kc + 32 + kb];
      w1 = *(const float4*)&Bsrc[kc + 32 + kb + 4];
    }
    bf16x8 afh[2], bfh[2];
#pragma unroll
    for (int i = 0; i < 2; ++i) {
      afh[i] = *(const bf16x8*)&Ahs[bfx][wm + i * 16 + fm][quad * 8];
      bfh[i] = *(const bf16x8*)&Bhs[bfx][wn + i * 16 + fm][quad * 8];
    }
    if (isproj) {
      bf16x8 afl[2], bfl[2];
#pragma unroll
      for (int i = 0; i < 2; ++i) {
        afl[i] = *(const bf16x8*)&Als[bfx][wm + i * 16 + fm][quad * 8];
        bfl[i] = *(const bf16x8*)&Bls[bfx][wn + i * 16 + fm][quad * 8];
      }
#pragma unroll
      for (int i = 0; i < 2; ++i)
#pragma unroll
        for (int j = 0; j < 2; ++j) {  // per-acc order hh,hl,lh == r7-r13
          acc[i][j] = __builtin_amdgcn_mfma_f32_16x16x32_bf16(afh[i], bfh[j], acc[i][j], 0, 0, 0);
          acc[i][j] = __builtin_amdgcn_mfma_f32_16x16x32_bf16(afh[i], bfl[j], acc[i][j], 0, 0, 0);
          acc[i][j] = __builtin_amdgcn_mfma_f32_16x16x32_bf16(afl[i], bfh[j], acc[i][j], 0, 0, 0);
        }
    } else {
#pragma unroll
      for (int i = 0; i < 2; ++i)
#pragma unroll
        for (int j = 0; j < 2; ++j)
          acc[i][j] = __builtin_amdgcn_mfma_f32_16x16x32_bf16(afh[i], bfh[j], acc[i][j], 0, 0, 0);
    }
  }
#pragma unroll
  for (int j = 0; j < 2; ++j) {
    const int col = n0 + wn + j * 16 + fm;
    if (col < 2 * H) {          // hijT[col][row]: float4 over 4 consecutive rows
      const float bias = (col < H) ? Wa_b[col] : Ua_b[col - H];
#pragma unroll
      for (int i = 0; i < 2; ++i) {
        float4 o;
        o.x = CSCALE * (acc[i][j][0] + bias);
        o.y = CSCALE * (acc[i][j][1] + bias);
        o.z = CSCALE * (acc[i][j][2] + bias);
        o.w = CSCALE * (acc[i][j][3] + bias);
        *(float4*)&hijT[(size_t)col * 1024 + m0 + wm + i * 16 + quad * 4] = o;
      }
    } else if (col < 3 * H) {   // dp: + dense_b, bf16
      const int o = col - 2 * H;
      const float bias = dense_b[o];
#pragma unroll
      for (int i = 0; i < 2; ++i)
#pragma unroll
        for (int rg = 0; rg < 4; ++rg) {
          const int row = m0 + wm + i * 16 + quad * 4 + rg;
          dpb[(size_t)row * H + o] = (__bf16)(acc[i][j][rg] + bias);
        }
    } else {                    // hp: raw, bf16
      const int o = col - 3 * H;
#pragma unroll
      for (int i = 0; i < 2; ++i)
#pragma unroll
        for (int rg = 0; rg < 4; ++rg) {
          const int row = m0 + wm + i * 16 + quad * 4 + rg;
          hpb[(size_t)row * H + o] = (__bf16)acc[i][j][rg];
        }
    }
  }
}

// ---------------------------------------------------------------------------
// Stage 2: partial[ch][b,a,c] = Sva_ch + sum_{96h} (-2 va[h]) * rcp(2^(xi+xj)+1)
// NH=8 (2048 blocks = 8/CU, r6-r12-validated grouping) + pk-fp32 inner loop
// (r13-validated, per-lane IEEE identical). Coalesced hijT loads (r12).
__global__ __launch_bounds__(256) void biaffine4(
    const float* __restrict__ hijT, const float* __restrict__ va,
    float* __restrict__ partials) {
  __shared__ __align__(16) float his[2][16][34];
  __shared__ __align__(16) float hjs[2][16][34];
  __shared__ __align__(16) float vas2[96];
  __shared__ float svas;
  const int z = blockIdx.z;
  const int b = z >> 3;
  const int ch = z & 7;
  const int hc0 = ch * 96;
  const int a0 = blockIdx.y * 32;
  const int c0 = blockIdx.x * 32;
  const int t = threadIdx.x;
  if (t < 96) vas2[t] = -2.f * va[hc0 + t];
  __syncthreads();
  if (t < 64) {
    float s = vas2[t] + ((t < 32) ? vas2[t + 64] : 0.f);
#pragma unroll
    for (int off = 32; off > 0; off >>= 1) s += __shfl_xor(s, off);
    if (t == 0) svas = -0.5f * s;
  }
  const int lh = t >> 4;       // h-index (slow)
  const int lr = t & 15;       // row-index (fast, coalesced)
  const int ca = (t & 15) * 2;
  const int aa = (t >> 4) * 2;
  const float* bi = hijT + (size_t)(hc0 + lh) * 1024 + b * S + c0 + lr;
  const float* bj = hijT + (size_t)(768 + hc0 + lh) * 1024 + b * S + a0 + lr;
  floatx2 acc0 = {0.f, 0.f}, acc1 = {0.f, 0.f};
  const floatx2 one = {1.f, 1.f};

  float pi0 = bi[0], pi1 = bi[16], pj0 = bj[0], pj1 = bj[16];
  for (int hr = 0; hr < 96; hr += 16) {
    const int bf = (hr >> 4) & 1;
    his[bf][lh][lr]      = pi0;
    his[bf][lh][lr + 16] = pi1;
    hjs[bf][lh][lr]      = pj0;
    hjs[bf][lh][lr + 16] = pj1;
    __syncthreads();
    if (hr + 16 < 96) {
      const size_t off = (size_t)(hr + 16) * 1024;
      pi0 = bi[off]; pi1 = bi[off + 16];
      pj0 = bj[off]; pj1 = bj[off + 16];
    }
    float vreg[16];
    *(float4*)&vreg[0]  = *(const float4*)&vas2[hr + 0];
    *(float4*)&vreg[4]  = *(const float4*)&vas2[hr + 4];
    *(float4*)&vreg[8]  = *(const float4*)&vas2[hr + 8];
    *(float4*)&vreg[12] = *(const float4*)&vas2[hr + 12];
#pragma unroll
    for (int h = 0; h < 16; ++h) {
      const float v = vreg[h];
      const floatx2 vv = {v, v};
      floatx2 xi = *(const floatx2*)&his[bf][h][ca];
      floatx2 xj = *(const floatx2*)&hjs[bf][h][aa];
      floatx2 t0 = xi + (floatx2){xj.x, xj.x};
      floatx2 t1 = xi + (floatx2){xj.y, xj.y};
      floatx2 e0 = {exp2_native(t0.x), exp2_native(t0.y)};
      floatx2 e1 = {exp2_native(t1.x), exp2_native(t1.y)};
      e0 = e0 + one;
      e1 = e1 + one;
      floatx2 r0 = {rcp_native(e0.x), rcp_native(e0.y)};
      floatx2 r1 = {rcp_native(e1.x), rcp_native(e1.y)};
      acc0 = fma2(vv, r0, acc0);
      acc1 = fma2(vv, r1, acc1);
    }
  }
  const float sv = svas;
  float* pout = partials + (size_t)ch * (NB * S * S);
  float2 r0 = {acc0.x + sv, acc0.y + sv};
  float2 r1 = {acc1.x + sv, acc1.y + sv};
  *(float2*)&pout[(b * S + a0 + aa) * S + c0 + ca]     = r0;
  *(float2*)&pout[(b * S + a0 + aa + 1) * S + c0 + ca] = r1;
}

// ---------------------------------------------------------------------------
// Stage 3 (256 threads): wave 0 combines 8 partials -> logits + top-4
// (combine order == r12, validated); candidates via LDS; each wave computes
// one candidate's type logits.
__global__ __launch_bounds__(256) void topk_final(
    const float* __restrict__ partials, const __bf16* __restrict__ dpb,
    const __bf16* __restrict__ hpb, const float* __restrict__ fc_w,
    const float* __restrict__ fc_b, float* __restrict__ logits,
    float* __restrict__ out_type) {
  __shared__ int scand[TOPK];
  const int row = blockIdx.x;  // b*S + a
  const int t = threadIdx.x;
  const int wave = t >> 6, lane = t & 63;
  if (wave == 0) {
    const int P = NB * S * S;
    float v[4];
#pragma unroll
    for (int j = 0; j < 4; ++j) {
      int c = row * S + j * 64 + lane;
      float s0 = partials[c]         + partials[c + P];
      float s1 = partials[c + 2 * P] + partials[c + 3 * P];
      float s2 = partials[c + 4 * P] + partials[c + 5 * P];
      float s3 = partials[c + 6 * P] + partials[c + 7 * P];
      v[j] = (s0 + s1) + (s2 + s3);
      logits[c] = v[j];
    }
#pragma unroll
    for (int k = 0; k < TOPK; ++k) {
      float bestv = v[0];
      int besti = lane;
#pragma unroll
      for (int j = 1; j < 4; ++j) {
        int c = j * 64 + lane;
        if (v[j] > bestv) { bestv = v[j]; besti = c; }
      }
#pragma unroll
      for (int off = 32; off > 0; off >>= 1) {
        float ov = __shfl_xor(bestv, off);
        int oi = __shfl_xor(besti, off);
        if (ov > bestv || (ov == bestv && oi < besti)) { bestv = ov; besti = oi; }
      }
      int mj = besti >> 6, ml = besti & 63;
#pragma unroll
      for (int j = 0; j < 4; ++j)
        if (lane == ml && j == mj) v[j] = -3.402823466e38f;
      if (lane == 0) scand[k] = besti;
    }
  }
  __syncthreads();
  const int k = wave;
  const __bf16* dp = dpb + (size_t)row * H;
  const int brow0 = (row >> 8) << 8;  // b*S
  const __bf16* hp = hpb + (size_t)(brow0 + scand[k]) * H;
  float acc[L] = {};
#pragma unroll
  for (int j = 0; j < 3; ++j) {
    const int o = j * 256 + lane * 4;
    bf16x4 dv = *(const bf16x4*)&dp[o];
    bf16x4 hv = *(const bf16x4*)&hp[o];
    float hd[4];
#pragma unroll
    for (int c = 0; c < 4; ++c)
      hd[c] = fast_tanh((float)dv[c] + (float)hv[c]);
#pragma unroll
    for (int l = 0; l < L; ++l) {
      float4 w = *(const float4*)&fc_w[l * H + o];
      acc[l] = fmaf(hd[0], w.x, acc[l]);
      acc[l] = fmaf(hd[1], w.y, acc[l]);
      acc[l] = fmaf(hd[2], w.z, acc[l]);
      acc[l] = fmaf(hd[3], w.w, acc[l]);
    }
  }
#pragma unroll
  for (int l = 0; l < L; ++l)
#pragma unroll
    for (int off = 32; off > 0; off >>= 1) acc[l] += __shfl_xor(acc[l], off);
  if (lane == 0) {
#pragma unroll
    for (int l = 0; l < L; ++l)
      out_type[((size_t)row * TOPK + k) * L + l] = acc[l] + fc_b[l];
  }
}

// ---------------------------------------------------------------------------
extern "C" void kernel_launch(void* const* d_in, const int* in_sizes, int n_in,
                              void* d_out, int out_size, void* d_ws, size_t ws_size,
                              hipStream_t stream) {
  const float* pooled  = (const float*)d_in[0];
  const float* Wa_w    = (const float*)d_in[1];
  const float* Wa_b    = (const float*)d_in[2];
  const float* Ua_w    = (const float*)d_in[3];
  const float* Ua_b    = (const float*)d_in[4];
  const float* va_w    = (const float*)d_in[5];
  const float* dense_w = (const float*)d_in[6];
  const float* dense_b = (const float*)d_in[7];
  const float* fc_w    = (const float*)d_in[8];
  const float* fc_b    = (const float*)d_in[9];

  float* logits   = (float*)d_out;            // (4,256,256)
  float* out_type = logits + NB * S * S;      // (4,256,4,4)

  // ws layout, 17.1 MB. mega writes hijT/dpb/hpb; biaffine reads hijT,
  // writes partials (8 planes); topk_final reads partials/dpb/hpb.
  float*  hijT     = (float*)d_ws;                   // 1536 x 1024 f (6 MB)
  float*  partials = hijT + 1572864;                 // 2097152 f (8 MB)
  __bf16* dpb      = (__bf16*)(partials + 2097152);  // 786432 bf16
  __bf16* hpb      = dpb + 786432;                   // 786432 bf16

  mega_mfma<<<dim3(16, 48), 256, 0, stream>>>(pooled, Wa_w, Ua_w, dense_w,
                                              Wa_b, Ua_b, dense_b,
                                              hijT, dpb, hpb);
  biaffine4<<<dim3(8, 8, NB * NH), 256, 0, stream>>>(hijT, va_w, partials);
  topk_final<<<dim3(1024), 256, 0, stream>>>(partials, dpb, hpb, fc_w, fc_b,
                                             logits, out_type);
}